// Round 10
// baseline (133.770 us; speedup 1.0000x reference)
//
#include <hip/hip_runtime.h>
#include <hip/hip_fp16.h>
#include <math.h>

typedef __attribute__((ext_vector_type(8))) _Float16 f16x8;
typedef __attribute__((ext_vector_type(4))) float f32x4;

__device__ __forceinline__ unsigned short f2h(float f) {
    __half h = __float2half_rn(f);
    union { __half h; unsigned short u; } v; v.h = h; return v.u;
}
__device__ __forceinline__ unsigned pk2h(float lo, float hi) {
    __half2 h = __floats2half2_rn(lo, hi);
    union { __half2 h; unsigned u; } v; v.h = h; return v.u;
}

// Raw barrier: LDS drained, global prefetch left in flight.
#define BARRIER() do { asm volatile("s_waitcnt lgkmcnt(0)" ::: "memory"); \
                       __builtin_amdgcn_s_barrier(); } while (0)

// Packed-f16 bilinear blend: 4 corner uint4s (8 f16 channels each) -> one uint4.
__device__ __forceinline__ void blend_store_h(uint4 uA, uint4 uB, uint4 uC, uint4 uD,
                                              __half2 w0, __half2 w1, __half2 w2, __half2 w3,
                                              unsigned short* dst) {
    union U { uint4 u; __half2 h[4]; };
    U a, b, c, d, r;
    a.u = uA; b.u = uB; c.u = uC; d.u = uD;
#pragma unroll
    for (int i = 0; i < 4; ++i)
        r.h[i] = __hfma2(w0, a.h[i], __hfma2(w1, b.h[i], __hfma2(w2, c.h[i], __hmul2(w3, d.h[i]))));
    *(uint4*)dst = r.u;
}

// ============ Fused prep kernel (block-specialized, coalesced A-fills) ============
// b==0          : offset net -> ipar/fpar
// b in [1,145)  : A2f  (LDS-staged coalesced tw gather)
// b in [145,289): Awf  (LDS-staged coalesced tw gather)
// b in [289,801): xp
// b in [801,931): zero upp halo
__global__ __launch_bounds__(256) void k_prep(const float* __restrict__ x,
                                              const float* __restrict__ lat,
                                              const float* __restrict__ tw,
                                              const float* __restrict__ w1,
                                              const float* __restrict__ b1,
                                              const float* __restrict__ w2,
                                              const float* __restrict__ b2,
                                              unsigned short* __restrict__ xp,
                                              unsigned short* __restrict__ A2f,
                                              unsigned short* __restrict__ Awf,
                                              unsigned short* __restrict__ upp,
                                              int* __restrict__ ipar,
                                              float* __restrict__ fpar) {
    __shared__ char smraw[36864];
    float* sm = (float*)smraw;
    unsigned short* smh = (unsigned short*)smraw;
    int b = blockIdx.x, t = threadIdx.x;
    if (b == 0) {
        for (int i = t; i < 8192; i += 256) sm[(i >> 7) * 129 + (i & 127)] = w1[i * 9 + 4];
        __syncthreads();
        if (t < 128) {
            int n = t >> 6, o = t & 63;
            float s = b1[o];
            const float* ln = lat + n * 128;
#pragma unroll 8
            for (int c = 0; c < 128; ++c) s += ln[c] * sm[o * 129 + c];
            sm[8256 + t] = fmaxf(s, 0.f);
        }
        __syncthreads();
        if (t < 36) {
            int n = t / 18, j = t % 18;
            float s = b2[j];
            for (int o = 0; o < 64; ++o) s += sm[8256 + n * 64 + o] * w2[(j * 64 + o) * 9 + 4];
            float ov = tanhf(s);
            ov = fminf(fmaxf(ov, -0.999999f), 0.999999f);
            sm[8384 + t] = ov;
        }
        __syncthreads();
        if (t < 36) {
            int n = t / 18, j = t % 18;
            int tap = j >> 1, d = j & 1;
            float ov = sm[8384 + t];
            float fl = floorf(ov);
            int kc = d ? (tap % 3) : (tap / 3);
            ipar[(n * 9 + tap) * 2 + d] = kc - 1 + (int)fl;
            fpar[(n * 9 + tap) * 2 + d] = ov - fl;
        }
    } else if (b < 145) {
        // A2f block: fixed (k, w) -> single tap, 64-row x 32-col tw slice.
        int bb_ = b - 1;
        int k = bb_ >> 2, w = bb_ & 3;      // k 0..35, w 0..3
        int tap = k >> 2;
        int c0 = (k & 3) * 32;
        for (int i = t * 4; i < 18432; i += 1024) {
            int r = i / 288;
            int cc = i - r * 288;
            const float* src = tw + (size_t)((w * 64 + r) * 128 + c0) * 9 + cc;
            float4 v4 = *(const float4*)src;
            smh[r * 288 + cc + 0] = f2h(v4.x);
            smh[r * 288 + cc + 1] = f2h(v4.y);
            smh[r * 288 + cc + 2] = f2h(v4.z);
            smh[r * 288 + cc + 3] = f2h(v4.w);
        }
        __syncthreads();
        int slot = bb_ * 256 + t;
        int l = t & 63;
        int mi = (t >> 6) & 3;
        int row_l = mi * 16 + (l & 15);
        int kq = l >> 4;
        unsigned short v[8];
#pragma unroll
        for (int j = 0; j < 8; ++j)
            v[j] = smh[row_l * 288 + (kq * 8 + j) * 9 + tap];
        unsigned p0 = (unsigned)v[0] | ((unsigned)v[1] << 16);
        unsigned p1 = (unsigned)v[2] | ((unsigned)v[3] << 16);
        unsigned p2 = (unsigned)v[4] | ((unsigned)v[5] << 16);
        unsigned p3 = (unsigned)v[6] | ((unsigned)v[7] << 16);
        *(uint4*)(A2f + slot * 8) = make_uint4(p0, p1, p2, p3);
    } else if (b < 289) {
        // Awf block: fixed (k, wm) -> single flipped tap, 32-ci x 64-row tw slice.
        int bb_ = b - 145;
        int k = bb_ >> 1, wm = bb_ & 1;     // k 0..71
        int t9 = k >> 3;
        int ci0 = (k & 7) * 32;
        int ky = t9 / 3, kx = t9 - ky * 3;
        int tapf = (2 - ky) * 3 + (2 - kx);
        for (int i = t * 4; i < 18432; i += 1024) {
            int cil = i / 576;
            int rr = i - cil * 576;
            const float* src = tw + (size_t)((ci0 + cil) * 128 + wm * 64) * 9 + rr;
            float4 v4 = *(const float4*)src;
            smh[cil * 576 + rr + 0] = f2h(v4.x);
            smh[cil * 576 + rr + 1] = f2h(v4.y);
            smh[cil * 576 + rr + 2] = f2h(v4.z);
            smh[cil * 576 + rr + 3] = f2h(v4.w);
        }
        __syncthreads();
        int slot = bb_ * 256 + t;
        int l = t & 63;
        int mi = (t >> 6) & 3;
        int row_l = mi * 16 + (l & 15);
        int kq = l >> 4;
        unsigned short v[8];
#pragma unroll
        for (int j = 0; j < 8; ++j)
            v[j] = smh[(kq * 8 + j) * 576 + row_l * 9 + tapf];
        unsigned p0 = (unsigned)v[0] | ((unsigned)v[1] << 16);
        unsigned p1 = (unsigned)v[2] | ((unsigned)v[3] << 16);
        unsigned p2 = (unsigned)v[4] | ((unsigned)v[5] << 16);
        unsigned p3 = (unsigned)v[6] | ((unsigned)v[7] << 16);
        *(uint4*)(Awf + slot * 8) = make_uint4(p0, p1, p2, p3);
    } else if (b < 801) {
        int bb = b - 289;
        int h = bb & 63, cq = (bb >> 6) & 3, n = bb >> 8;
        int c0 = cq * 64;
        {
            int wcol = t & 63, sub = t >> 6;
            for (int r = 0; r < 16; ++r) {
                int ci_l = r * 4 + sub;
                sm[ci_l * 65 + wcol] = x[((n * 256 + c0 + ci_l) * 64 + h) * 64 + wcol];
            }
        }
        __syncthreads();
        int wcol = t >> 2, cg = t & 3;
        unsigned short* dst = xp + (size_t)n * (65 * 65 * 256) + (h * 65 + wcol) * 256 + c0 + cg * 16;
        unsigned pk[8];
#pragma unroll
        for (int j = 0; j < 8; ++j)
            pk[j] = pk2h(sm[(cg * 16 + 2 * j) * 65 + wcol], sm[(cg * 16 + 2 * j + 1) * 65 + wcol]);
        *(uint4*)dst = make_uint4(pk[0], pk[1], pk[2], pk[3]);
        *(uint4*)(dst + 8) = make_uint4(pk[4], pk[5], pk[6], pk[7]);
    } else {
        // zero upp halo: rows {0,1,130,131} full width + cols {0,1,130,131} of rows 2..129
        int g = (b - 801) * 256 + t;          // 0..33279
        int n2 = g >= 16640 ? 1 : 0;
        int i = g - n2 * 16640;               // 0..16639
        int px_id = i >> 4, chv = i & 15;
        int r, c;
        if (px_id < 528) {
            int rr = px_id / 132;
            r = rr < 2 ? rr : 128 + rr;       // 0,1,130,131
            c = px_id - rr * 132;
        } else {
            int jj = px_id - 528;             // 0..511
            r = 2 + (jj >> 2);                // 2..129
            int cc = jj & 3;
            c = cc < 2 ? cc : 128 + cc;       // 0,1,130,131
        }
        uint4* p = (uint4*)(upp + (size_t)n2 * (132 * 132 * 128) + ((r * 132 + c) * 128) + chv * 8);
        *p = make_uint4(0u, 0u, 0u, 0u);
    }
}

// ============ tconv: parity-decomposed MFMA GEMM, 2 K-chunks per barrier phase (R4) ======
__global__ __launch_bounds__(256) void k_tconv3(const unsigned short* __restrict__ xp,
                                                const unsigned short* __restrict__ Awf,
                                                unsigned short* __restrict__ upp) {
    __shared__ unsigned short Bs[2][2][64][40];   // [buf][chunk][px][40]
    __shared__ int st9[4];
    __shared__ int sbb[4];
    int t = threadIdx.x;
    int b = blockIdx.x;
    int phase = b & 1;
    int xpar = ((b >> 1) & 1) ^ phase;
    int n = (b >> 2) & 1;
    int yh = b >> 3;                 // 0..63
    int y = yh * 2 + phase;
    const unsigned short* xpn = xp + (size_t)n * (65 * 65 * 256);

    int lane = t & 63, w = t >> 6;
    int col = lane & 15, q = lane >> 4;
    int wm = w >> 1, wn = w & 1;
    int bx = t >> 2, bcg = t & 3;
    int boff = bx * 256 + bcg * 8;

    int kys[2], kxs[2], nky, nkx;
    if (phase) { kys[0] = 0; kys[1] = 2; nky = 2; } else { kys[0] = 1; kys[1] = 1; nky = 1; }
    if (xpar)  { kxs[0] = 0; kxs[1] = 2; nkx = 2; } else { kxs[0] = 1; kxs[1] = 1; nkx = 1; }
    int nslots = nky * nkx;
    if (t < 4) {
        int tc = t < nslots ? t : 0;
        int a1 = (nkx == 2) ? (tc >> 1) : tc;
        int a2 = (nkx == 2) ? (tc & 1) : 0;
        int ky = kys[a1], kx = kxs[a2];
        st9[t] = ky * 3 + kx;
        int d2 = (y + ky - 1) >> 1;
        int s = (xpar + kx - 1) >> 1;
        sbb[t] = (d2 * 65 + s) * 256;
    }
    int NPAIR = nslots * 4;          // 4 / 8 / 16

    f32x4 acc[4][2];
#pragma unroll
    for (int mi = 0; mi < 4; ++mi)
#pragma unroll
        for (int ni = 0; ni < 2; ++ni) acc[mi][ni] = (f32x4){0.f, 0.f, 0.f, 0.f};

    __syncthreads();   // st9/sbb visible

    const unsigned short* Afw = Awf + wm * 2048 + lane * 8;  // + kA*4096 + mi*512
    f16x8 aC[2][4], aN[2][4];
    uint4 nb0, nb1;

    // prologue: pair 0 (chunks 0,1 of slot 0)
    {
        const unsigned short* pT = xpn + sbb[0] + boff;
        uint4 b0 = *(const uint4*)pT;
        uint4 b1 = *(const uint4*)(pT + 32);
        const unsigned short* ap = Afw + st9[0] * 32768;
#pragma unroll
        for (int mi = 0; mi < 4; ++mi) {
            aC[0][mi] = *(const f16x8*)(ap + mi * 512);
            aC[1][mi] = *(const f16x8*)(ap + 4096 + mi * 512);
        }
        *(uint4*)&Bs[0][0][bx][bcg * 8] = b0;
        *(uint4*)&Bs[0][1][bx][bcg * 8] = b1;
    }
    BARRIER();

#define TC_PH(PP, BUF, AC, AN)                                                   \
    {                                                                            \
        int P_ = (PP);                                                           \
        if (P_ + 1 < NPAIR) {                                                    \
            int slot_ = (P_ + 1) >> 2;                                           \
            int cb0_ = ((P_ + 1) & 3) * 2;                                       \
            const unsigned short* pT_ = xpn + sbb[slot_] + cb0_ * 32 + boff;     \
            nb0 = *(const uint4*)pT_;                                            \
            nb1 = *(const uint4*)(pT_ + 32);                                     \
            const unsigned short* ap_ = Afw + (st9[slot_] * 8 + cb0_) * 4096;    \
            _Pragma("unroll")                                                    \
            for (int mi = 0; mi < 4; ++mi) {                                     \
                AN[0][mi] = *(const f16x8*)(ap_ + mi * 512);                     \
                AN[1][mi] = *(const f16x8*)(ap_ + 4096 + mi * 512);              \
            }                                                                    \
        }                                                                        \
        f16x8 bb[2][2];                                                          \
        _Pragma("unroll")                                                        \
        for (int c = 0; c < 2; ++c)                                              \
            _Pragma("unroll")                                                    \
            for (int ni = 0; ni < 2; ++ni)                                       \
                bb[c][ni] = *(const f16x8*)&Bs[BUF][c][wn * 32 + ni * 16 + col][q * 8]; \
        _Pragma("unroll")                                                        \
        for (int c = 0; c < 2; ++c)                                              \
            _Pragma("unroll")                                                    \
            for (int mi = 0; mi < 4; ++mi)                                       \
                _Pragma("unroll")                                                \
                for (int ni = 0; ni < 2; ++ni)                                   \
                    acc[mi][ni] = __builtin_amdgcn_mfma_f32_16x16x32_f16(AC[c][mi], bb[c][ni], acc[mi][ni], 0, 0, 0); \
        if (P_ + 1 < NPAIR) {                                                    \
            *(uint4*)&Bs[BUF ^ 1][0][bx][bcg * 8] = nb0;                         \
            *(uint4*)&Bs[BUF ^ 1][1][bx][bcg * 8] = nb1;                         \
        }                                                                        \
        BARRIER();                                                               \
    }

    for (int pp = 0; pp < NPAIR; pp += 2) {
        TC_PH(pp,     0, aC, aN);
        TC_PH(pp + 1, 1, aN, aC);
    }
#undef TC_PH

    unsigned short* uppn = upp + (size_t)n * (132 * 132 * 128);
#pragma unroll
    for (int mi = 0; mi < 4; ++mi)
#pragma unroll
        for (int ni = 0; ni < 2; ++ni) {
            int co = wm * 64 + mi * 16 + q * 4;
            int p64 = wn * 32 + ni * 16 + col;
            int xg = 2 * p64 + xpar;
            unsigned short* p = uppn + ((y + 2) * 132 + (xg + 2)) * 128 + co;
            unsigned lo = pk2h(acc[mi][ni][0], acc[mi][ni][1]);
            unsigned hi = pk2h(acc[mi][ni][2], acc[mi][ni][3]);
            *(uint2*)p = make_uint2(lo, hi);
        }
}

// ============ deform: LDS-windowed bilinear + MFMA GEMM (R8, unchanged) ============
__global__ __launch_bounds__(256) void k_deform4(const unsigned short* __restrict__ upp,
                                                 const unsigned short* __restrict__ A2f,
                                                 const int* __restrict__ ipar,
                                                 const float* __restrict__ fpar,
                                                 float* __restrict__ out) {
    __shared__ unsigned short Ws[2][5][68][32];   // [chunk][row][px][ch]  43,520 B
    __shared__ unsigned short Bs[2][2][64][40];   // [buf][chunk][px][40]  20,480 B
    __shared__ int sR0[9], sDx[9];
    __shared__ __half2 swh[9][4];
    int t = threadIdx.x;
    int b = blockIdx.x;
    int xcd = b & 7, j = b >> 3;          // j in [0,64)
    int n = xcd >> 2, band = xcd & 3;
    int y = band * 32 + (j & 31);
    int tx0 = (j >> 5) * 64;              // 2 strips of 64
    const unsigned short* uppn = upp + (size_t)n * (132 * 132 * 128);

    int lane = t & 63, w = t >> 6;
    int col = lane & 15, q = lane >> 4;
    int bx = t >> 2, bcg = t & 3;         // px 0..63, 8-ch group 0..3

    if (t < 9) {
        int iy = ipar[(n * 9 + t) * 2 + 0], ix = ipar[(n * 9 + t) * 2 + 1];
        float fy = fpar[(n * 9 + t) * 2 + 0], fx = fpar[(n * 9 + t) * 2 + 1];
        sR0[t] = iy + 2;                  // 0..3
        sDx[t] = ix + 2;                  // 0..3
        swh[t][0] = __float2half2_rn((1.f - fy) * (1.f - fx));
        swh[t][1] = __float2half2_rn((1.f - fy) * fx);
        swh[t][2] = __float2half2_rn(fy * (1.f - fx));
        swh[t][3] = __float2half2_rn(fy * fx);
    }

    f32x4 acc[4][4];
#pragma unroll
    for (int mi = 0; mi < 4; ++mi)
#pragma unroll
        for (int ni = 0; ni < 4; ++ni) acc[mi][ni] = (f32x4){0.f, 0.f, 0.f, 0.f};

    __syncthreads();   // sR0/sDx/swh visible

    const unsigned short* Afw = A2f + w * 2048 + lane * 8;   // + k*8192 + mi*512
    f16x8 aC[2][4], aN[2][4];

#define BLEND_WS(CHUNK, TAP, DST)                                                \
    {                                                                            \
        int r0_ = sR0[TAP], dx_ = sDx[TAP];                                      \
        const unsigned short* pA_ = &Ws[CHUNK][0][0][0] + (r0_ * 68 + bx + dx_) * 32 + bcg * 8; \
        uint4 uA_ = *(const uint4*)pA_;                                          \
        uint4 uB_ = *(const uint4*)(pA_ + 32);                                   \
        uint4 uC_ = *(const uint4*)(pA_ + 68 * 32);                              \
        uint4 uD_ = *(const uint4*)(pA_ + 68 * 32 + 32);                         \
        blend_store_h(uA_, uB_, uC_, uD_, swh[TAP][0], swh[TAP][1],              \
                      swh[TAP][2], swh[TAP][3], DST);                            \
    }

#define DEF_TAU(TAU, BUF, AC, AN, S)                                             \
    {                                                                            \
        if ((TAU) < 8) {                                                         \
            const unsigned short* ap_ = Afw + (((TAU) + 1) * 4 + (S) * 2) * 8192;\
            _Pragma("unroll")                                                    \
            for (int mi = 0; mi < 4; ++mi) {                                     \
                AN[0][mi] = *(const f16x8*)(ap_ + mi * 512);                     \
                AN[1][mi] = *(const f16x8*)(ap_ + 8192 + mi * 512);              \
            }                                                                    \
        }                                                                        \
        f16x8 bb[2][4];                                                          \
        _Pragma("unroll")                                                        \
        for (int c = 0; c < 2; ++c)                                              \
            _Pragma("unroll")                                                    \
            for (int ni = 0; ni < 4; ++ni)                                       \
                bb[c][ni] = *(const f16x8*)&Bs[BUF][c][ni * 16 + col][q * 8];    \
        _Pragma("unroll")                                                        \
        for (int c = 0; c < 2; ++c)                                              \
            _Pragma("unroll")                                                    \
            for (int mi = 0; mi < 4; ++mi)                                       \
                _Pragma("unroll")                                                \
                for (int ni = 0; ni < 4; ++ni)                                   \
                    acc[mi][ni] = __builtin_amdgcn_mfma_f32_16x16x32_f16(AC[c][mi], bb[c][ni], acc[mi][ni], 0, 0, 0); \
        if ((TAU) < 8) {                                                         \
            BLEND_WS(0, (TAU) + 1, &Bs[BUF ^ 1][0][bx][bcg * 8]);                \
            BLEND_WS(1, (TAU) + 1, &Bs[BUF ^ 1][1][bx][bcg * 8]);                \
        }                                                                        \
        BARRIER();                                                               \
    }

    for (int s = 0; s < 2; ++s) {
        // ---- stage 5x68x64 window for ch [s*64, s*64+64) ----
        for (int i = t; i < 2720; i += 256) {
            int c2 = i / 1360;
            int rem2 = i - c2 * 1360;
            int row = rem2 / 272;
            int rem = rem2 - row * 272;
            int px = rem >> 2, cg4 = rem & 3;
            uint4 v = *(const uint4*)&uppn[(size_t)((y + row) * 132 + tx0 + px) * 128 + s * 64 + c2 * 32 + cg4 * 8];
            *(uint4*)(&Ws[c2][0][0][0] + (row * 68 + px) * 32 + cg4 * 8) = v;
        }
        BARRIER();
        // ---- prologue: blend tap 0, load A for (tap0, s) ----
        {
            const unsigned short* ap0 = Afw + s * 16384;
#pragma unroll
            for (int mi = 0; mi < 4; ++mi) {
                aC[0][mi] = *(const f16x8*)(ap0 + mi * 512);
                aC[1][mi] = *(const f16x8*)(ap0 + 8192 + mi * 512);
            }
            BLEND_WS(0, 0, &Bs[0][0][bx][bcg * 8]);
            BLEND_WS(1, 0, &Bs[0][1][bx][bcg * 8]);
        }
        BARRIER();
        DEF_TAU(0, 0, aC, aN, s);
        DEF_TAU(1, 1, aN, aC, s);
        DEF_TAU(2, 0, aC, aN, s);
        DEF_TAU(3, 1, aN, aC, s);
        DEF_TAU(4, 0, aC, aN, s);
        DEF_TAU(5, 1, aN, aC, s);
        DEF_TAU(6, 0, aC, aN, s);
        DEF_TAU(7, 1, aN, aC, s);
        DEF_TAU(8, 0, aC, aN, s);
    }
#undef DEF_TAU
#undef BLEND_WS

#pragma unroll
    for (int mi = 0; mi < 4; ++mi)
#pragma unroll
        for (int ni = 0; ni < 4; ++ni) {
            int o = w * 64 + mi * 16 + q * 4;
            int xg = tx0 + ni * 16 + col;
            float* p = out + (((size_t)(n * 256 + o)) * 128 + y) * 128 + xg;
            p[0]         = acc[mi][ni][0];
            p[16384]     = acc[mi][ni][1];
            p[2 * 16384] = acc[mi][ni][2];
            p[3 * 16384] = acc[mi][ni][3];
        }
}

extern "C" void kernel_launch(void* const* d_in, const int* in_sizes, int n_in,
                              void* d_out, int out_size, void* d_ws, size_t ws_size,
                              hipStream_t stream) {
    const float* x   = (const float*)d_in[0];
    const float* lat = (const float*)d_in[1];
    const float* tw  = (const float*)d_in[2];
    const float* w1  = (const float*)d_in[3];
    const float* b1  = (const float*)d_in[4];
    const float* w2  = (const float*)d_in[5];
    const float* b2  = (const float*)d_in[6];
    float* out = (float*)d_out;

    char* ws = (char*)d_ws;
    // upp f16 halo2: 2*132*132*128*2 = 8,921,088 @ 0          (halo zeroed in k_prep)
    // xp  f16 pad+1: 2*65*65*256*2   = 4,326,400 @ 8,921,088  (memset)
    // A2f: 294912*2 = 589,824 @ 13,247,488
    // Awf: 294912*2 = 589,824 @ 13,837,312
    unsigned short* upp = (unsigned short*)ws;
    unsigned short* xp  = (unsigned short*)(ws + 8921088);
    unsigned short* A2f = (unsigned short*)(ws + 13247488);
    unsigned short* Awf = (unsigned short*)(ws + 13837312);
    int*   ipar         = (int*)(ws + 14427136);
    float* fpar         = (float*)(ws + 14427424);

    hipMemsetAsync(ws + 8921088, 0, 4326400, stream);
    k_prep<<<931, 256, 0, stream>>>(x, lat, tw, w1, b1, w2, b2, xp, A2f, Awf, upp, ipar, fpar);
    k_tconv3<<<512, 256, 0, stream>>>(xp, Awf, upp);
    k_deform4<<<512, 256, 0, stream>>>(upp, A2f, ipar, fpar, out);
}

// Round 11
// 128.323 us; speedup vs baseline: 1.0424x; 1.0424x over previous
//
#include <hip/hip_runtime.h>
#include <hip/hip_fp16.h>
#include <math.h>

typedef __attribute__((ext_vector_type(8))) _Float16 f16x8;
typedef __attribute__((ext_vector_type(4))) float f32x4;

__device__ __forceinline__ unsigned short f2h(float f) {
    __half h = __float2half_rn(f);
    union { __half h; unsigned short u; } v; v.h = h; return v.u;
}
__device__ __forceinline__ unsigned pk2h(float lo, float hi) {
    __half2 h = __floats2half2_rn(lo, hi);
    union { __half2 h; unsigned u; } v; v.h = h; return v.u;
}

// Raw barrier: LDS drained, global prefetch left in flight.
#define BARRIER() do { asm volatile("s_waitcnt lgkmcnt(0)" ::: "memory"); \
                       __builtin_amdgcn_s_barrier(); } while (0)

// Packed-f16 bilinear blend: 4 corner uint4s (8 f16 channels each) -> one uint4.
__device__ __forceinline__ void blend_store_h(uint4 uA, uint4 uB, uint4 uC, uint4 uD,
                                              __half2 w0, __half2 w1, __half2 w2, __half2 w3,
                                              unsigned short* dst) {
    union U { uint4 u; __half2 h[4]; };
    U a, b, c, d, r;
    a.u = uA; b.u = uB; c.u = uC; d.u = uD;
#pragma unroll
    for (int i = 0; i < 4; ++i)
        r.h[i] = __hfma2(w0, a.h[i], __hfma2(w1, b.h[i], __hfma2(w2, c.h[i], __hmul2(w3, d.h[i]))));
    *(uint4*)dst = r.u;
}

// ============ Fused prep kernel (block-specialized) ============
// b==0          : offset net -> ipar/fpar
// b in [1,145)  : A2f  (scattered tw gather -- measured faster than LDS staging, R10)
// b in [145,289): Awf
// b in [289,801): xp
// b in [801,931): zero upp halo
// b in [931,964): zero xp pad (row 64 / col 64) -- replaces the 4.3MB memset
__global__ __launch_bounds__(256) void k_prep(const float* __restrict__ x,
                                              const float* __restrict__ lat,
                                              const float* __restrict__ tw,
                                              const float* __restrict__ w1,
                                              const float* __restrict__ b1,
                                              const float* __restrict__ w2,
                                              const float* __restrict__ b2,
                                              unsigned short* __restrict__ xp,
                                              unsigned short* __restrict__ A2f,
                                              unsigned short* __restrict__ Awf,
                                              unsigned short* __restrict__ upp,
                                              int* __restrict__ ipar,
                                              float* __restrict__ fpar) {
    __shared__ float sm[8420];
    int b = blockIdx.x, t = threadIdx.x;
    if (b == 0) {
        for (int i = t; i < 8192; i += 256) sm[(i >> 7) * 129 + (i & 127)] = w1[i * 9 + 4];
        __syncthreads();
        if (t < 128) {
            int n = t >> 6, o = t & 63;
            float s = b1[o];
            const float* ln = lat + n * 128;
#pragma unroll 8
            for (int c = 0; c < 128; ++c) s += ln[c] * sm[o * 129 + c];
            sm[8256 + t] = fmaxf(s, 0.f);
        }
        __syncthreads();
        if (t < 36) {
            int n = t / 18, j = t % 18;
            float s = b2[j];
            for (int o = 0; o < 64; ++o) s += sm[8256 + n * 64 + o] * w2[(j * 64 + o) * 9 + 4];
            float ov = tanhf(s);
            ov = fminf(fmaxf(ov, -0.999999f), 0.999999f);
            sm[8384 + t] = ov;
        }
        __syncthreads();
        if (t < 36) {
            int n = t / 18, j = t % 18;
            int tap = j >> 1, d = j & 1;
            float ov = sm[8384 + t];
            float fl = floorf(ov);
            int kc = d ? (tap % 3) : (tap / 3);
            ipar[(n * 9 + tap) * 2 + d] = kc - 1 + (int)fl;
            fpar[(n * 9 + tap) * 2 + d] = ov - fl;
        }
    } else if (b < 145) {
        int slot = (b - 1) * 256 + t;
        int l = slot & 63;
        int mi = (slot >> 6) & 3;
        int w = (slot >> 8) & 3;
        int k = slot >> 10;                 // 0..35
        int row = w * 64 + mi * 16 + (l & 15);
        int kq = l >> 4;
        unsigned short v[8];
#pragma unroll
        for (int j = 0; j < 8; ++j) {
            int kcol = k * 32 + kq * 8 + j;  // < 1152
            int tap = kcol >> 7, c = kcol & 127;
            v[j] = f2h(tw[(row * 128 + c) * 9 + tap]);
        }
        unsigned p0 = (unsigned)v[0] | ((unsigned)v[1] << 16);
        unsigned p1 = (unsigned)v[2] | ((unsigned)v[3] << 16);
        unsigned p2 = (unsigned)v[4] | ((unsigned)v[5] << 16);
        unsigned p3 = (unsigned)v[6] | ((unsigned)v[7] << 16);
        *(uint4*)(A2f + slot * 8) = make_uint4(p0, p1, p2, p3);
    } else if (b < 289) {
        int slot = (b - 145) * 256 + t;
        int l = slot & 63;
        int mi = (slot >> 6) & 3;
        int wm = (slot >> 8) & 1;
        int k = slot >> 9;                  // 0..71
        int row = wm * 64 + mi * 16 + (l & 15);
        int kq = l >> 4;
        unsigned short v[8];
#pragma unroll
        for (int j = 0; j < 8; ++j) {
            int kcol = k * 32 + kq * 8 + j;  // < 2304
            int t9 = kcol >> 8, ci = kcol & 255;
            int ky = t9 / 3, kx = t9 - ky * 3;
            v[j] = f2h(tw[(ci * 128 + row) * 9 + (2 - ky) * 3 + (2 - kx)]);
        }
        unsigned p0 = (unsigned)v[0] | ((unsigned)v[1] << 16);
        unsigned p1 = (unsigned)v[2] | ((unsigned)v[3] << 16);
        unsigned p2 = (unsigned)v[4] | ((unsigned)v[5] << 16);
        unsigned p3 = (unsigned)v[6] | ((unsigned)v[7] << 16);
        *(uint4*)(Awf + slot * 8) = make_uint4(p0, p1, p2, p3);
    } else if (b < 801) {
        int bb = b - 289;
        int h = bb & 63, cq = (bb >> 6) & 3, n = bb >> 8;
        int c0 = cq * 64;
        {
            int wcol = t & 63, sub = t >> 6;
            for (int r = 0; r < 16; ++r) {
                int ci_l = r * 4 + sub;
                sm[ci_l * 65 + wcol] = x[((n * 256 + c0 + ci_l) * 64 + h) * 64 + wcol];
            }
        }
        __syncthreads();
        int wcol = t >> 2, cg = t & 3;
        unsigned short* dst = xp + (size_t)n * (65 * 65 * 256) + (h * 65 + wcol) * 256 + c0 + cg * 16;
        unsigned pk[8];
#pragma unroll
        for (int j = 0; j < 8; ++j)
            pk[j] = pk2h(sm[(cg * 16 + 2 * j) * 65 + wcol], sm[(cg * 16 + 2 * j + 1) * 65 + wcol]);
        *(uint4*)dst = make_uint4(pk[0], pk[1], pk[2], pk[3]);
        *(uint4*)(dst + 8) = make_uint4(pk[4], pk[5], pk[6], pk[7]);
    } else if (b < 931) {
        // zero upp halo: rows {0,1,130,131} full width + cols {0,1,130,131} of rows 2..129
        int g = (b - 801) * 256 + t;          // 0..33279
        int n2 = g >= 16640 ? 1 : 0;
        int i = g - n2 * 16640;               // 0..16639
        int px_id = i >> 4, chv = i & 15;
        int r, c;
        if (px_id < 528) {
            int rr = px_id / 132;
            r = rr < 2 ? rr : 128 + rr;       // 0,1,130,131
            c = px_id - rr * 132;
        } else {
            int jj = px_id - 528;             // 0..511
            r = 2 + (jj >> 2);                // 2..129
            int cc = jj & 3;
            c = cc < 2 ? cc : 128 + cc;       // 0,1,130,131
        }
        uint4* p = (uint4*)(upp + (size_t)n2 * (132 * 132 * 128) + ((r * 132 + c) * 128) + chv * 8);
        *p = make_uint4(0u, 0u, 0u, 0u);
    } else {
        // zero xp pad: row h=64 (65 px) + col wcol=64 (h 0..63) per image.
        // 129 px x 32 uint4 x 2 images = 8256 stores.
        int g = (b - 931) * 256 + t;          // 0..8447
        if (g < 8256) {
            int n2 = g >= 4128 ? 1 : 0;
            int i = g - n2 * 4128;            // 0..4127
            int px_id = i >> 5, chv = i & 31; // px 0..128, 32 x uint4 (256 ch)
            int h, wcol;
            if (px_id < 65) { h = 64; wcol = px_id; }
            else            { h = px_id - 65; wcol = 64; }
            uint4* p = (uint4*)(xp + (size_t)n2 * (65 * 65 * 256) + (h * 65 + wcol) * 256 + chv * 8);
            *p = make_uint4(0u, 0u, 0u, 0u);
        }
    }
}

// ============ tconv: parity-decomposed MFMA GEMM, 2 K-chunks per barrier phase (R4/R8) ===
__global__ __launch_bounds__(256) void k_tconv3(const unsigned short* __restrict__ xp,
                                                const unsigned short* __restrict__ Awf,
                                                unsigned short* __restrict__ upp) {
    __shared__ unsigned short Bs[2][2][64][40];   // [buf][chunk][px][40]
    __shared__ int st9[4];
    __shared__ int sbb[4];
    int t = threadIdx.x;
    int b = blockIdx.x;
    int phase = b & 1;
    int xpar = ((b >> 1) & 1) ^ phase;
    int n = (b >> 2) & 1;
    int yh = b >> 3;                 // 0..63
    int y = yh * 2 + phase;
    const unsigned short* xpn = xp + (size_t)n * (65 * 65 * 256);

    int lane = t & 63, w = t >> 6;
    int col = lane & 15, q = lane >> 4;
    int wm = w >> 1, wn = w & 1;
    int bx = t >> 2, bcg = t & 3;
    int boff = bx * 256 + bcg * 8;

    int kys[2], kxs[2], nky, nkx;
    if (phase) { kys[0] = 0; kys[1] = 2; nky = 2; } else { kys[0] = 1; kys[1] = 1; nky = 1; }
    if (xpar)  { kxs[0] = 0; kxs[1] = 2; nkx = 2; } else { kxs[0] = 1; kxs[1] = 1; nkx = 1; }
    int nslots = nky * nkx;
    if (t < 4) {
        int tc = t < nslots ? t : 0;
        int a1 = (nkx == 2) ? (tc >> 1) : tc;
        int a2 = (nkx == 2) ? (tc & 1) : 0;
        int ky = kys[a1], kx = kxs[a2];
        st9[t] = ky * 3 + kx;
        int d2 = (y + ky - 1) >> 1;
        int s = (xpar + kx - 1) >> 1;
        sbb[t] = (d2 * 65 + s) * 256;
    }
    int NPAIR = nslots * 4;          // 4 / 8 / 16

    f32x4 acc[4][2];
#pragma unroll
    for (int mi = 0; mi < 4; ++mi)
#pragma unroll
        for (int ni = 0; ni < 2; ++ni) acc[mi][ni] = (f32x4){0.f, 0.f, 0.f, 0.f};

    __syncthreads();   // st9/sbb visible

    const unsigned short* Afw = Awf + wm * 2048 + lane * 8;  // + kA*4096 + mi*512
    f16x8 aC[2][4], aN[2][4];
    uint4 nb0, nb1;

    // prologue: pair 0 (chunks 0,1 of slot 0)
    {
        const unsigned short* pT = xpn + sbb[0] + boff;
        uint4 b0 = *(const uint4*)pT;
        uint4 b1 = *(const uint4*)(pT + 32);
        const unsigned short* ap = Afw + st9[0] * 32768;
#pragma unroll
        for (int mi = 0; mi < 4; ++mi) {
            aC[0][mi] = *(const f16x8*)(ap + mi * 512);
            aC[1][mi] = *(const f16x8*)(ap + 4096 + mi * 512);
        }
        *(uint4*)&Bs[0][0][bx][bcg * 8] = b0;
        *(uint4*)&Bs[0][1][bx][bcg * 8] = b1;
    }
    BARRIER();

#define TC_PH(PP, BUF, AC, AN)                                                   \
    {                                                                            \
        int P_ = (PP);                                                           \
        if (P_ + 1 < NPAIR) {                                                    \
            int slot_ = (P_ + 1) >> 2;                                           \
            int cb0_ = ((P_ + 1) & 3) * 2;                                       \
            const unsigned short* pT_ = xpn + sbb[slot_] + cb0_ * 32 + boff;     \
            nb0 = *(const uint4*)pT_;                                            \
            nb1 = *(const uint4*)(pT_ + 32);                                     \
            const unsigned short* ap_ = Afw + (st9[slot_] * 8 + cb0_) * 4096;    \
            _Pragma("unroll")                                                    \
            for (int mi = 0; mi < 4; ++mi) {                                     \
                AN[0][mi] = *(const f16x8*)(ap_ + mi * 512);                     \
                AN[1][mi] = *(const f16x8*)(ap_ + 4096 + mi * 512);              \
            }                                                                    \
        }                                                                        \
        f16x8 bb[2][2];                                                          \
        _Pragma("unroll")                                                        \
        for (int c = 0; c < 2; ++c)                                              \
            _Pragma("unroll")                                                    \
            for (int ni = 0; ni < 2; ++ni)                                       \
                bb[c][ni] = *(const f16x8*)&Bs[BUF][c][wn * 32 + ni * 16 + col][q * 8]; \
        _Pragma("unroll")                                                        \
        for (int c = 0; c < 2; ++c)                                              \
            _Pragma("unroll")                                                    \
            for (int mi = 0; mi < 4; ++mi)                                       \
                _Pragma("unroll")                                                \
                for (int ni = 0; ni < 2; ++ni)                                   \
                    acc[mi][ni] = __builtin_amdgcn_mfma_f32_16x16x32_f16(AC[c][mi], bb[c][ni], acc[mi][ni], 0, 0, 0); \
        if (P_ + 1 < NPAIR) {                                                    \
            *(uint4*)&Bs[BUF ^ 1][0][bx][bcg * 8] = nb0;                         \
            *(uint4*)&Bs[BUF ^ 1][1][bx][bcg * 8] = nb1;                         \
        }                                                                        \
        BARRIER();                                                               \
    }

    for (int pp = 0; pp < NPAIR; pp += 2) {
        TC_PH(pp,     0, aC, aN);
        TC_PH(pp + 1, 1, aN, aC);
    }
#undef TC_PH

    unsigned short* uppn = upp + (size_t)n * (132 * 132 * 128);
#pragma unroll
    for (int mi = 0; mi < 4; ++mi)
#pragma unroll
        for (int ni = 0; ni < 2; ++ni) {
            int co = wm * 64 + mi * 16 + q * 4;
            int p64 = wn * 32 + ni * 16 + col;
            int xg = 2 * p64 + xpar;
            unsigned short* p = uppn + ((y + 2) * 132 + (xg + 2)) * 128 + co;
            unsigned lo = pk2h(acc[mi][ni][0], acc[mi][ni][1]);
            unsigned hi = pk2h(acc[mi][ni][2], acc[mi][ni][3]);
            *(uint2*)p = make_uint2(lo, hi);
        }
}

// ============ deform: LDS-windowed bilinear + MFMA GEMM (R8, unchanged) ============
__global__ __launch_bounds__(256) void k_deform4(const unsigned short* __restrict__ upp,
                                                 const unsigned short* __restrict__ A2f,
                                                 const int* __restrict__ ipar,
                                                 const float* __restrict__ fpar,
                                                 float* __restrict__ out) {
    __shared__ unsigned short Ws[2][5][68][32];   // [chunk][row][px][ch]  43,520 B
    __shared__ unsigned short Bs[2][2][64][40];   // [buf][chunk][px][40]  20,480 B
    __shared__ int sR0[9], sDx[9];
    __shared__ __half2 swh[9][4];
    int t = threadIdx.x;
    int b = blockIdx.x;
    int xcd = b & 7, j = b >> 3;          // j in [0,64)
    int n = xcd >> 2, band = xcd & 3;
    int y = band * 32 + (j & 31);
    int tx0 = (j >> 5) * 64;              // 2 strips of 64
    const unsigned short* uppn = upp + (size_t)n * (132 * 132 * 128);

    int lane = t & 63, w = t >> 6;
    int col = lane & 15, q = lane >> 4;
    int bx = t >> 2, bcg = t & 3;         // px 0..63, 8-ch group 0..3

    if (t < 9) {
        int iy = ipar[(n * 9 + t) * 2 + 0], ix = ipar[(n * 9 + t) * 2 + 1];
        float fy = fpar[(n * 9 + t) * 2 + 0], fx = fpar[(n * 9 + t) * 2 + 1];
        sR0[t] = iy + 2;                  // 0..3
        sDx[t] = ix + 2;                  // 0..3
        swh[t][0] = __float2half2_rn((1.f - fy) * (1.f - fx));
        swh[t][1] = __float2half2_rn((1.f - fy) * fx);
        swh[t][2] = __float2half2_rn(fy * (1.f - fx));
        swh[t][3] = __float2half2_rn(fy * fx);
    }

    f32x4 acc[4][4];
#pragma unroll
    for (int mi = 0; mi < 4; ++mi)
#pragma unroll
        for (int ni = 0; ni < 4; ++ni) acc[mi][ni] = (f32x4){0.f, 0.f, 0.f, 0.f};

    __syncthreads();   // sR0/sDx/swh visible

    const unsigned short* Afw = A2f + w * 2048 + lane * 8;   // + k*8192 + mi*512
    f16x8 aC[2][4], aN[2][4];

#define BLEND_WS(CHUNK, TAP, DST)                                                \
    {                                                                            \
        int r0_ = sR0[TAP], dx_ = sDx[TAP];                                      \
        const unsigned short* pA_ = &Ws[CHUNK][0][0][0] + (r0_ * 68 + bx + dx_) * 32 + bcg * 8; \
        uint4 uA_ = *(const uint4*)pA_;                                          \
        uint4 uB_ = *(const uint4*)(pA_ + 32);                                   \
        uint4 uC_ = *(const uint4*)(pA_ + 68 * 32);                              \
        uint4 uD_ = *(const uint4*)(pA_ + 68 * 32 + 32);                         \
        blend_store_h(uA_, uB_, uC_, uD_, swh[TAP][0], swh[TAP][1],              \
                      swh[TAP][2], swh[TAP][3], DST);                            \
    }

#define DEF_TAU(TAU, BUF, AC, AN, S)                                             \
    {                                                                            \
        if ((TAU) < 8) {                                                         \
            const unsigned short* ap_ = Afw + (((TAU) + 1) * 4 + (S) * 2) * 8192;\
            _Pragma("unroll")                                                    \
            for (int mi = 0; mi < 4; ++mi) {                                     \
                AN[0][mi] = *(const f16x8*)(ap_ + mi * 512);                     \
                AN[1][mi] = *(const f16x8*)(ap_ + 8192 + mi * 512);              \
            }                                                                    \
        }                                                                        \
        f16x8 bb[2][4];                                                          \
        _Pragma("unroll")                                                        \
        for (int c = 0; c < 2; ++c)                                              \
            _Pragma("unroll")                                                    \
            for (int ni = 0; ni < 4; ++ni)                                       \
                bb[c][ni] = *(const f16x8*)&Bs[BUF][c][ni * 16 + col][q * 8];    \
        _Pragma("unroll")                                                        \
        for (int c = 0; c < 2; ++c)                                              \
            _Pragma("unroll")                                                    \
            for (int mi = 0; mi < 4; ++mi)                                       \
                _Pragma("unroll")                                                \
                for (int ni = 0; ni < 4; ++ni)                                   \
                    acc[mi][ni] = __builtin_amdgcn_mfma_f32_16x16x32_f16(AC[c][mi], bb[c][ni], acc[mi][ni], 0, 0, 0); \
        if ((TAU) < 8) {                                                         \
            BLEND_WS(0, (TAU) + 1, &Bs[BUF ^ 1][0][bx][bcg * 8]);                \
            BLEND_WS(1, (TAU) + 1, &Bs[BUF ^ 1][1][bx][bcg * 8]);                \
        }                                                                        \
        BARRIER();                                                               \
    }

    for (int s = 0; s < 2; ++s) {
        // ---- stage 5x68x64 window for ch [s*64, s*64+64) ----
        for (int i = t; i < 2720; i += 256) {
            int c2 = i / 1360;
            int rem2 = i - c2 * 1360;
            int row = rem2 / 272;
            int rem = rem2 - row * 272;
            int px = rem >> 2, cg4 = rem & 3;
            uint4 v = *(const uint4*)&uppn[(size_t)((y + row) * 132 + tx0 + px) * 128 + s * 64 + c2 * 32 + cg4 * 8];
            *(uint4*)(&Ws[c2][0][0][0] + (row * 68 + px) * 32 + cg4 * 8) = v;
        }
        BARRIER();
        // ---- prologue: blend tap 0, load A for (tap0, s) ----
        {
            const unsigned short* ap0 = Afw + s * 16384;
#pragma unroll
            for (int mi = 0; mi < 4; ++mi) {
                aC[0][mi] = *(const f16x8*)(ap0 + mi * 512);
                aC[1][mi] = *(const f16x8*)(ap0 + 8192 + mi * 512);
            }
            BLEND_WS(0, 0, &Bs[0][0][bx][bcg * 8]);
            BLEND_WS(1, 0, &Bs[0][1][bx][bcg * 8]);
        }
        BARRIER();
        DEF_TAU(0, 0, aC, aN, s);
        DEF_TAU(1, 1, aN, aC, s);
        DEF_TAU(2, 0, aC, aN, s);
        DEF_TAU(3, 1, aN, aC, s);
        DEF_TAU(4, 0, aC, aN, s);
        DEF_TAU(5, 1, aN, aC, s);
        DEF_TAU(6, 0, aC, aN, s);
        DEF_TAU(7, 1, aN, aC, s);
        DEF_TAU(8, 0, aC, aN, s);
    }
#undef DEF_TAU
#undef BLEND_WS

#pragma unroll
    for (int mi = 0; mi < 4; ++mi)
#pragma unroll
        for (int ni = 0; ni < 4; ++ni) {
            int o = w * 64 + mi * 16 + q * 4;
            int xg = tx0 + ni * 16 + col;
            float* p = out + (((size_t)(n * 256 + o)) * 128 + y) * 128 + xg;
            p[0]         = acc[mi][ni][0];
            p[16384]     = acc[mi][ni][1];
            p[2 * 16384] = acc[mi][ni][2];
            p[3 * 16384] = acc[mi][ni][3];
        }
}

extern "C" void kernel_launch(void* const* d_in, const int* in_sizes, int n_in,
                              void* d_out, int out_size, void* d_ws, size_t ws_size,
                              hipStream_t stream) {
    const float* x   = (const float*)d_in[0];
    const float* lat = (const float*)d_in[1];
    const float* tw  = (const float*)d_in[2];
    const float* w1  = (const float*)d_in[3];
    const float* b1  = (const float*)d_in[4];
    const float* w2  = (const float*)d_in[5];
    const float* b2  = (const float*)d_in[6];
    float* out = (float*)d_out;

    char* ws = (char*)d_ws;
    // upp f16 halo2: 2*132*132*128*2 = 8,921,088 @ 0          (halo zeroed in k_prep)
    // xp  f16 pad+1: 2*65*65*256*2   = 4,326,400 @ 8,921,088  (pad zeroed in k_prep)
    // A2f: 294912*2 = 589,824 @ 13,247,488
    // Awf: 294912*2 = 589,824 @ 13,837,312
    unsigned short* upp = (unsigned short*)ws;
    unsigned short* xp  = (unsigned short*)(ws + 8921088);
    unsigned short* A2f = (unsigned short*)(ws + 13247488);
    unsigned short* Awf = (unsigned short*)(ws + 13837312);
    int*   ipar         = (int*)(ws + 14427136);
    float* fpar         = (float*)(ws + 14427424);

    k_prep<<<964, 256, 0, stream>>>(x, lat, tw, w1, b1, w2, b2, xp, A2f, Awf, upp, ipar, fpar);
    k_tconv3<<<512, 256, 0, stream>>>(xp, Awf, upp);
    k_deform4<<<512, 256, 0, stream>>>(upp, A2f, ipar, fpar, out);
}